// Round 7
// baseline (278.998 us; speedup 1.0000x reference)
//
#include <hip/hip_runtime.h>
#include <cstdint>

typedef unsigned short u16;
typedef __attribute__((ext_vector_type(8))) short bf16x8;
typedef __attribute__((ext_vector_type(4))) float f32x4;

#define B_    128
#define P_    2048
#define NC_   10
#define F_    160      // NC*CLO
#define NPROD 512      // producer blocks (2 per CU)
#define NRED  80       // reducer blocks appended after producers
#define PPB   4        // p-tiles per producer block (all 4 LDS-resident)
#define NTHR  512
#define WLS   162      // k_prep w LDS stride: k0-offsets {0,8,16,24} -> 2-way max
#define XTS   520      // k_prep x tile p-stride (shorts): p_local*4 banks, 2-way max

__device__ __forceinline__ u16 f2bf(float f) {
    union { float f; unsigned u; } v; v.f = f;
    unsigned r = v.u + 0x7FFFu + ((v.u >> 16) & 1u);   // RNE
    return (u16)(r >> 16);
}
__device__ __forceinline__ float bf2f(u16 h) {
    union { unsigned u; float f; } v; v.u = ((unsigned)h) << 16;
    return v.f;
}

// async global->LDS, 16B per lane; LDS dest = wave-uniform base + lane*16.
__device__ __forceinline__ void gl_lds16(const void* g, void* l) {
    typedef __attribute__((address_space(3))) unsigned lds_uint;
    typedef __attribute__((address_space(1))) const unsigned glob_uint;
    __builtin_amdgcn_global_load_lds((glob_uint*)(uintptr_t)g,
                                     (lds_uint*)(unsigned)(uintptr_t)l, 16, 0, 0);
}

// Fused prep + counter zeroing.
// Blocks 0..255: x part, LDS tile-transpose. Tile = 64 p x 16 b. Reads coalesced
// over p; squash along NP=32 (quad shfl); writes xb[p][b*32 + swz] as 1KB-contiguous
// wave bursts (fixes R6's 64x16B@4KB-stride scatter). Byte-identical xb vs R6.
// Blocks 256..2303: w[p][k][f] fp32 -> wb[p] bf16 transposed (1KB-contig writes).
__global__ void k_prep(const float* __restrict__ t, const float* __restrict__ w,
                       u16* __restrict__ xb, u16* __restrict__ wb,
                       int* __restrict__ cnt) {
    const int blk = blockIdx.x, tid = threadIdx.x;
    if (blk == 0 && tid < 3) cnt[tid] = 0;    // pass completion counters
    if (blk < 256) {
        __shared__ u16 tile[64 * XTS];        // 66560 B
        const int pt = blk >> 3, bt = blk & 7;
        const int p0 = pt * 64, b0 = bt * 16;
        const int pl = tid >> 2, sub = tid & 3;
        const float4* tg = (const float4*)t;
#pragma unroll
        for (int bl = 0; bl < 16; ++bl) {
            int b = b0 + bl;
            int fi = (b * P_ + p0 + pl) * 8 + sub * 2;
            float4 va = tg[fi], vb = tg[fi + 1];
            float ss = va.x*va.x + va.y*va.y + va.z*va.z + va.w*va.w
                     + vb.x*vb.x + vb.y*vb.y + vb.z*vb.z + vb.w*vb.w;
            ss += __shfl_xor(ss, 1);          // quad (same b,p) holds full 32-sum
            ss += __shfl_xor(ss, 2);
            float fct = ss / ((1.f + ss) * sqrtf(ss));
            u16 h[8] __attribute__((aligned(16)));
            h[0]=f2bf(va.x*fct); h[1]=f2bf(va.y*fct); h[2]=f2bf(va.z*fct); h[3]=f2bf(va.w*fct);
            h[4]=f2bf(vb.x*fct); h[5]=f2bf(vb.y*fct); h[6]=f2bf(vb.z*fct); h[7]=f2bf(vb.w*fct);
            int off = (sub + (bl >> 1)) & 3;  // == (sub + (b>>1))&3 since b0 % 4 paired
            *(uint4*)&tile[pl * XTS + bl * 32 + off * 8] = *(const uint4*)h;
        }
        __syncthreads();
        const int wv = tid >> 6, L = tid & 63;
#pragma unroll
        for (int it = 0; it < 16; ++it) {
            int p = p0 + it * 4 + wv;         // one wave: one p-row, 1KB contiguous
            *(uint4*)(xb + p * 4096 + b0 * 32 + L * 8) =
                *(const uint4*)&tile[(it * 4 + wv) * XTS + L * 8];
        }
    } else {
        __shared__ u16 wl[32 * WLS];
        int p = blk - 256;
        const float4* wp = (const float4*)(w + p * 32 * F_);
        for (int e4 = tid; e4 < 1280; e4 += 256) {
            float4 v = wp[e4];
            int k = e4 / 40, fg = e4 % 40;
            u16 h[4] __attribute__((aligned(8)));
            h[0]=f2bf(v.x); h[1]=f2bf(v.y); h[2]=f2bf(v.z); h[3]=f2bf(v.w);
            *(ushort4*)(wl + k * WLS + fg * 4) = *(const ushort4*)h;
        }
        __syncthreads();
        u16* wo = wb + p * 5120;
        for (int sid = tid; sid < 640; sid += 256) {
            int f = sid >> 2, k0 = (sid & 3) << 3, q = sid & 3;
            u16 tmp[8] __attribute__((aligned(16)));
#pragma unroll
            for (int j = 0; j < 8; ++j) tmp[j] = wl[(k0 + j) * WLS + f];
            int off = (q + (f >> 1)) & 3;
            *(uint4*)(wo + f * 32 + off * 8) = *(const uint4*)tmp;
        }
    }
}

// One tile's compute (unchanged from R6): fine vmcnt + raw barrier.
template<int PP, int MODE>
__device__ __forceinline__ void tile_step(
    const u16* __restrict__ xt, const u16* __restrict__ wt,
    f32x4 (&s_acc)[NC_], const float4 (&vv)[NC_],
    int wv, int b, int col, int off8)
{
    if (wv < 2) __builtin_amdgcn_s_waitcnt(0x0f70 | (3 * (3 - PP)));
    else        __builtin_amdgcn_s_waitcnt(0x0f70 | (2 * (3 - PP)));
    __builtin_amdgcn_s_barrier();

    bf16x8 bfrag = *(const bf16x8*)&xt[b * 32 + off8];
    if (MODE == 0) {
#pragma unroll
        for (int n = 0; n < NC_; ++n) {
            bf16x8 afrag = *(const bf16x8*)&wt[(n * 16 + col) * 32 + off8];
            s_acc[n] = __builtin_amdgcn_mfma_f32_16x16x32_bf16(afrag, bfrag, s_acc[n], 0, 0, 0);
        }
    } else {
        float tt[NC_];
#pragma unroll
        for (int n = 0; n < NC_; ++n) {
            bf16x8 afrag = *(const bf16x8*)&wt[(n * 16 + col) * 32 + off8];
            f32x4 z = {0.f, 0.f, 0.f, 0.f};
            f32x4 acc = __builtin_amdgcn_mfma_f32_16x16x32_bf16(afrag, bfrag, z, 0, 0, 0);
            float t = acc[0]*vv[n].x + acc[1]*vv[n].y + acc[2]*vv[n].z + acc[3]*vv[n].w;
            t += __shfl_xor(t, 16);
            t += __shfl_xor(t, 32);
            tt[n] = t;
        }
        float mx = tt[0];
#pragma unroll
        for (int n = 1; n < NC_; ++n) mx = fmaxf(mx, tt[n]);
        float den = 0.f;
#pragma unroll
        for (int n = 0; n < NC_; ++n) { tt[n] = __expf(tt[n] - mx); den += tt[n]; }
        float inv = 1.f / den;
#pragma unroll
        for (int n = 0; n < NC_; ++n) {
            bf16x8 afrag = *(const bf16x8*)&wt[(n * 16 + col) * 32 + off8];
            f32x4 z = {0.f, 0.f, 0.f, 0.f};
            f32x4 acc = __builtin_amdgcn_mfma_f32_16x16x32_bf16(afrag, bfrag, z, 0, 0, 0);
            float cf = tt[n] * inv;
#pragma unroll
            for (int r = 0; r < 4; ++r) s_acc[n][r] += cf * acc[r];
        }
    }
}

// Fused routing pass + reduction. Blocks 0..511: producers (R6 core + counter
// release). Blocks 512..591: reducers -- spin on agent-scope counter, then sum
// bf16 partials over 512 producer blocks, squash along CLO=16, write v.
// MODE 0: c=0.1, vout=v0. MODE 1: logits u.v0, vout=v0+squash(s)=vs.
// MODE 2: logits u.vs, vout=out.
template<int MODE>
__global__ __launch_bounds__(NTHR, 2) void k_pass(
        const u16* __restrict__ xb, const u16* __restrict__ wb,
        const float* __restrict__ vprev, u16* __restrict__ s_part,
        int* __restrict__ cnt, float* __restrict__ vout)
{
    __shared__ __align__(16) u16 xt[PPB][4096];
    __shared__ __align__(16) u16 wt[PPB][5120];
    const int tid = threadIdx.x, blk = blockIdx.x;

    if (blk < NPROD) {
        const int L = tid & 63, wv = tid >> 6;
        const int q = L >> 4, col = L & 15;
        const int b = wv * 16 + col;
        const int p0 = blk * PPB;
        const int off8 = ((q + (col >> 1)) & 3) * 8;

        float4 vv[NC_];
        if (MODE != 0) {      // issued first: oldest in vmcnt order
#pragma unroll
            for (int n = 0; n < NC_; ++n)
                vv[n] = *(const float4*)(vprev + b * F_ + n * 16 + q * 4);
        }
#pragma unroll
        for (int t = 0; t < PPB; ++t) {
            int p = p0 + t;
            gl_lds16(xb + p * 4096 + wv * 512 + L * 8, &xt[t][wv * 512]);
            gl_lds16(wb + p * 5120 + wv * 512 + L * 8, &wt[t][wv * 512]);
            if (wv < 2)
                gl_lds16(wb + p * 5120 + (8 + wv) * 512 + L * 8, &wt[t][(8 + wv) * 512]);
        }

        f32x4 s_acc[NC_];
#pragma unroll
        for (int n = 0; n < NC_; ++n) s_acc[n] = (f32x4){0.f, 0.f, 0.f, 0.f};

        tile_step<0, MODE>(xt[0], wt[0], s_acc, vv, wv, b, col, off8);
        tile_step<1, MODE>(xt[1], wt[1], s_acc, vv, wv, b, col, off8);
        tile_step<2, MODE>(xt[2], wt[2], s_acc, vv, wv, b, col, off8);
        tile_step<3, MODE>(xt[3], wt[3], s_acc, vv, wv, b, col, off8);

        __syncthreads();
        u16* ls = &wt[0][0];
        const float sc = (MODE == 0) ? 0.1f : 1.f;
#pragma unroll
        for (int n = 0; n < NC_; ++n) {
            u16 h[4] __attribute__((aligned(8)));
#pragma unroll
            for (int r = 0; r < 4; ++r) h[r] = f2bf(s_acc[n][r] * sc);
            *(ushort4*)&ls[b * F_ + n * 16 + q * 4] = *(const ushort4*)h;
        }
        __syncthreads();
        const uint4* lsv = (const uint4*)ls;
        uint4* gp = (uint4*)(s_part + blk * (B_ * F_));
#pragma unroll
        for (int i = 0; i < 5; ++i)
            gp[i * 512 + tid] = lsv[i * 512 + tid];

        __syncthreads();                 // all stores issued block-wide
        if (tid == 0) {
            __threadfence();             // agent-scope release of s_part
            atomicAdd(cnt, 1);
        }
    } else {
        // ---- reducer ----
        const int rblk = blk - NPROD;    // 0..79, 128 uint-pairs each
        if (tid == 0) {
            while (__hip_atomic_load(cnt, __ATOMIC_RELAXED,
                                     __HIP_MEMORY_SCOPE_AGENT) < NPROD)
                __builtin_amdgcn_s_sleep(16);
            __threadfence();             // acquire: s_part visible
        }
        __syncthreads();
        const int pid = tid & 127, part = tid >> 7;
        const int o = rblk * 128 + pid;
        const uint* sp = (const uint*)s_part;
        float a0 = 0.f, a1 = 0.f;
#pragma unroll 8
        for (int g = part; g < NPROD; g += 4) {
            uint u = sp[g * 10240 + o];
            a0 += bf2f((u16)(u & 0xffff));
            a1 += bf2f((u16)(u >> 16));
        }
        float* rs = (float*)&xt[0][0];   // reuse LDS: 2x512 floats
        rs[tid] = a0; rs[512 + tid] = a1;
        __syncthreads();
        if (tid < 128) {
            float s0 = rs[tid] + rs[tid + 128] + rs[tid + 256] + rs[tid + 384];
            float s1 = rs[512 + tid] + rs[640 + tid] + rs[768 + tid] + rs[896 + tid];
            float sq = s0 * s0 + s1 * s1;
            sq += __shfl_xor(sq, 1);     // 8 threads = 16 elems of one (b,n)
            sq += __shfl_xor(sq, 2);
            sq += __shfl_xor(sq, 4);
            float fct = sq / ((1.f + sq) * sqrtf(sq));
            float2 res = make_float2(s0 * fct, s1 * fct);
            if (MODE == 1) {             // vs = v0 + squash(s)
                float2 pv = *(const float2*)(vprev + 2 * o);
                res.x += pv.x; res.y += pv.y;
            }
            *(float2*)(vout + 2 * o) = res;
        }
    }
}

extern "C" void kernel_launch(void* const* d_in, const int* in_sizes, int n_in,
                              void* d_out, int out_size, void* d_ws, size_t ws_size,
                              hipStream_t stream) {
    const float* tensor = (const float*)d_in[0];
    const float* weight = (const float*)d_in[1];
    float* out = (float*)d_out;
    char* ws = (char*)d_ws;

    u16*   xb     = (u16*)(ws);                       // 16,777,216 B
    u16*   wb     = (u16*)(ws + 16777216);            // 20,971,520 B
    u16*   s_part = (u16*)(ws + 37748736);            // 512*20480*2 = 20,971,520 B
    float* v0     = (float*)(ws + 58720256);          // 81,920 B
    float* vs     = (float*)(ws + 58802176);          // 81,920 B (v0 + v1)
    int*   cnt    = (int*)(ws + 58884096);            // 3 pass counters

    k_prep<<<2304, 256, 0, stream>>>(tensor, weight, xb, wb, cnt);

    k_pass<0><<<NPROD + NRED, NTHR, 0, stream>>>(xb, wb, nullptr, s_part, cnt + 0, v0);
    k_pass<1><<<NPROD + NRED, NTHR, 0, stream>>>(xb, wb, v0,      s_part, cnt + 1, vs);
    k_pass<2><<<NPROD + NRED, NTHR, 0, stream>>>(xb, wb, vs,      s_part, cnt + 2, out);
}